// Round 6
// baseline (818.109 us; speedup 1.0000x reference)
//
#include <hip/hip_runtime.h>
#include <cstdint>
#include <cstddef>

typedef float v4f __attribute__((ext_vector_type(4)));
typedef short short8 __attribute__((ext_vector_type(8)));

constexpr int B_ = 8, P_ = 16384, Q_ = 256, E_ = 128;

// ---------- helpers ----------
__device__ __forceinline__ unsigned int f2bf(float f) {
  unsigned int x = __float_as_uint(f);
  x += 0x7FFFu + ((x >> 16) & 1u);           // round-to-nearest-even
  return x >> 16;
}
__device__ __forceinline__ float softplus_f(float x) {
  return fmaxf(x, 0.f) + __logf(1.f + __expf(-fabsf(x)));
}
__device__ __forceinline__ float wsum(float v) {
#pragma unroll
  for (int o = 32; o; o >>= 1) v += __shfl_xor(v, o, 64);
  return v;
}
// LDS-only barrier (no vmcnt drain); proven correct in R1.
__device__ __forceinline__ void lds_barrier() {
  asm volatile("s_waitcnt lgkmcnt(0)" ::: "memory");
  __builtin_amdgcn_s_barrier();
}
// q-major LDS word address with 3-bit XOR swizzle (word bits 2-4 ^= q bits 3-5).
// Bijective (each bit XORed with strictly-higher bits). Keeps 16B read blocks
// and 8B write pairs contiguous (word bits 0-1 untouched).
__device__ __forceinline__ int swz(int q, int kp) {
  return ((q << 4) | kp) ^ (((q >> 3) & 7) << 2);
}

// ---------- fused: prep + both GEMMs, split-K x64 ----------
// R5 lesson: iteration time invariant to LDS op count, VALU packing, atomics,
// and barrier vmcnt semantics -> stall-bound with 1 barrier-locked block/CU
// (2 waves/SIMD: no independent work to hide latency). R6: split-K 32 -> 64,
// grid 512 blocks = 2 independent blocks/CU (4 waves/SIMD, LDS 96<=160KB,
// regs 1024<=2048/SIMD). Inner loop unchanged from R5 (zero spill risk).
template<bool DIRECT>
__global__ __launch_bounds__(512, 4) void fused_all(
    const float* __restrict__ mlv, const int* __restrict__ mask,
    const float* __restrict__ seg, float* __restrict__ part,
    float* __restrict__ negsum, float* __restrict__ ppsum,
    float* __restrict__ segsum, float* __restrict__ nnzb)
{
  __shared__ __align__(16) unsigned int lds[12288];   // 49152 B
  unsigned int* A1q = lds;            // 256q x 16 words
  unsigned int* EZq = lds + 4096;     // 256q x 16
  unsigned int* SBq = lds + 8192;     // 128e x 16
  unsigned int* STq = lds + 10240;    // 128e x 16

  const int t = threadIdx.x, w = t >> 6, l = t & 63;
  const int lm = l & 15, quad = l >> 4;
  const int wr = w & 3, wc = w >> 2;
  const int jj = l >> 5, le = l & 31;
  const int b = blockIdx.x >> 6, ks = blockIdx.x & 63;

  v4f acc0[4][4], acc1[4][4];
#pragma unroll
  for (int i = 0; i < 4; ++i)
#pragma unroll
    for (int j = 0; j < 4; ++j) { acc0[i][j] = (v4f)0.f; acc1[i][j] = (v4f)0.f; }
  float accN[4] = {0.f,0.f,0.f,0.f};
  float accP[4] = {0.f,0.f,0.f,0.f};
  float accS[4] = {0.f,0.f,0.f,0.f};
  float cnt = 0.f;

  const float* mp = mlv + ((size_t)b * P_ + ks * 256 + 4 * w) * Q_ + 4 * l;
  const int*   kp = mask + ((size_t)b * P_ + ks * 256 + 4 * w) * Q_ + 4 * l;
  const float* sp = seg + ((size_t)b * P_ + ks * 256 + 4 * w + 2 * jj) * E_ + 4 * le;

  float4 X[4]; int4 M[4]; float4 S0, S1;
#pragma unroll
  for (int r = 0; r < 4; ++r) {
    X[r] = *(const float4*)(mp + (size_t)r * Q_);
    M[r] = *(const int4*)(kp + (size_t)r * Q_);
  }
  S0 = *(const float4*)(sp);
  S1 = *(const float4*)(sp + E_);

  for (int it = 0; it < 8; ++it) {
    // ---- unpack & compute ----
    float xs[4][4]; int ms[4][4];
#pragma unroll
    for (int r = 0; r < 4; ++r) {
      xs[r][0] = X[r].x; xs[r][1] = X[r].y; xs[r][2] = X[r].z; xs[r][3] = X[r].w;
      ms[r][0] = M[r].x; ms[r][1] = M[r].y; ms[r][2] = M[r].z; ms[r][3] = M[r].w;
    }
    float sv0[4] = {S0.x, S0.y, S0.z, S0.w};
    float sv1[4] = {S1.x, S1.y, S1.z, S1.w};

    // ---- prefetch next step (issues early, completes during this iter) ----
    if (it < 7) {
      mp += 32 * Q_; kp += 32 * Q_; sp += 32 * E_;
#pragma unroll
      for (int r = 0; r < 4; ++r) {
        X[r] = *(const float4*)(mp + (size_t)r * Q_);
        M[r] = *(const int4*)(kp + (size_t)r * Q_);
      }
      S0 = *(const float4*)(sp);
      S1 = *(const float4*)(sp + E_);
    }

    float ez[4][4], rs[4];
#pragma unroll
    for (int r = 0; r < 4; ++r) {
      float s = 0.f;
#pragma unroll
      for (int j = 0; j < 4; ++j) {
        const bool mm = ms[r][j] != 0;
        const float e = mm ? __expf(xs[r][j]) : 0.f;
        ez[r][j] = e; s += e;
        accN[j] += __logf(1.f + e);                    // softplus(x) on masked
      }
      rs[r] = s;
    }
#pragma unroll
    for (int r = 0; r < 4; ++r) rs[r] = wsum(rs[r]);
    float inv[4];
#pragma unroll
    for (int r = 0; r < 4; ++r) inv[r] = (rs[r] > 0.f) ? (1.f / rs[r]) : 0.f;

    unsigned int a1p[2][4], ezp[2][4];
#pragma unroll
    for (int jp = 0; jp < 2; ++jp)
#pragma unroll
      for (int j = 0; j < 4; ++j) {
        const int r0 = 2 * jp, r1 = 2 * jp + 1;
        a1p[jp][j] = f2bf(ms[r0][j] ? -xs[r0][j] : 0.f)
                   | (f2bf(ms[r1][j] ? -xs[r1][j] : 0.f) << 16);
        const float p0 = ez[r0][j] * inv[r0];
        const float p1 = ez[r1][j] * inv[r1];
        accP[j] += p0 + p1;
        ezp[jp][j] = f2bf(p0) | (f2bf(p1) << 16);
      }
    unsigned int sb[4], st_[4];
#pragma unroll
    for (int j = 0; j < 4; ++j) {
      accS[j] += sv0[j] + sv1[j];
      cnt += ((sv0[j] > 0.f) ? 1.f : 0.f) + ((sv1[j] > 0.f) ? 1.f : 0.f);
      sb[j]  = ((sv0[j] > 0.f) ? 0x3F80u : 0u) | ((sv1[j] > 0.f) ? 0x3F800000u : 0u);
      st_[j] = f2bf(sv0[j]) | (f2bf(sv1[j]) << 16);
    }

    lds_barrier();   // previous MFMA phase done reading LDS
    // A/EZ: thread owns q = 4l..4l+3, kp pair {2w, 2w+1} -> uint2 (b64) each.
#pragma unroll
    for (int j = 0; j < 4; ++j) {
      const int q = 4 * l + j;
      const int wa = swz(q, 2 * w);
      uint2 va; va.x = a1p[0][j]; va.y = a1p[1][j];
      uint2 ve; ve.x = ezp[0][j]; ve.y = ezp[1][j];
      *(uint2*)(A1q + wa) = va;
      *(uint2*)(EZq + wa) = ve;
    }
    // SB/ST: thread owns e = 4le..4le+3, single word kp = 2w+jj.
#pragma unroll
    for (int j = 0; j < 4; ++j) {
      const int e = 4 * le + j;
      const int wb = swz(e, 2 * w + jj);
      SBq[wb] = sb[j];
      STq[wb] = st_[j];
    }
    lds_barrier();   // writes visible to all waves

    // ---- MFMA phase: k=32, one ds_read_b128 per fragment ----
    short8 af0[4], af1[4], bf0[4], bf1[4];
#pragma unroll
    for (int i = 0; i < 4; ++i) {
      const int q_abs = wr * 64 + i * 16 + lm;
      const int wa = swz(q_abs, 4 * quad);
      af0[i] = *(const short8*)(A1q + wa);
      af1[i] = *(const short8*)(EZq + wa);
    }
#pragma unroll
    for (int j = 0; j < 4; ++j) {
      const int e_abs = wc * 64 + j * 16 + lm;
      const int wb = swz(e_abs, 4 * quad);
      bf0[j] = *(const short8*)(SBq + wb);
      bf1[j] = *(const short8*)(STq + wb);
    }
#pragma unroll
    for (int i = 0; i < 4; ++i)
#pragma unroll
      for (int j = 0; j < 4; ++j) {
        acc0[i][j] = __builtin_amdgcn_mfma_f32_16x16x32_bf16(af0[i], bf0[j], acc0[i][j], 0, 0, 0);
        acc1[i][j] = __builtin_amdgcn_mfma_f32_16x16x32_bf16(af1[i], bf1[j], acc1[i][j], 0, 0, 0);
      }
  }

  // ---- small reductions (negsum/ppsum/segsum/nnz) ----
  __syncthreads();
  float* fr = (float*)lds;
#pragma unroll
  for (int j = 0; j < 4; ++j) {
    fr[w * 256 + 4 * l + j] = accN[j];
    fr[2048 + w * 256 + 4 * l + j] = accP[j];
    fr[4096 + (2 * w + jj) * 128 + 4 * le + j] = accS[j];
  }
  __syncthreads();
  if (t < 256) {
    float sn = 0.f, sq = 0.f;
#pragma unroll
    for (int k = 0; k < 8; ++k) { sn += fr[k * 256 + t]; sq += fr[2048 + k * 256 + t]; }
    atomicAdd(&negsum[b * 256 + t], sn);
    atomicAdd(&ppsum[b * 256 + t], sq);
  } else if (t < 384) {
    const int e = t - 256;
    float ss = 0.f;
#pragma unroll
    for (int k = 0; k < 16; ++k) ss += fr[4096 + k * 128 + e];
    atomicAdd(&segsum[b * 128 + e], ss);
  }
  cnt = wsum(cnt);
  if (l == 0) atomicAdd(&nnzb[b], cnt);

  // ---- split-K partials ----
  if constexpr (DIRECT) {
    // private per-block slices, plain coalesced stores; epilogue reduces 64.
    float* p0 = part + ((size_t)(ks * 8 + b) * 2) * 32768;
    float* p1 = p0 + 32768;
#pragma unroll
    for (int i = 0; i < 4; ++i)
#pragma unroll
      for (int r = 0; r < 4; ++r) {
        const int q = wr * 64 + i * 16 + quad * 4 + r;
#pragma unroll
        for (int j = 0; j < 4; ++j) {
          const int e = wc * 64 + j * 16 + lm;
          p0[q * 128 + e] = acc0[i][j][r];
          p1[q * 128 + e] = acc1[i][j][r];
        }
      }
  } else {
    float* p0 = part + (size_t)b * 32768;
    float* p1 = part + (size_t)(8 + b) * 32768;
#pragma unroll
    for (int i = 0; i < 4; ++i)
#pragma unroll
      for (int r = 0; r < 4; ++r) {
        const int q = wr * 64 + i * 16 + quad * 4 + r;
#pragma unroll
        for (int j = 0; j < 4; ++j) {
          const int e = wc * 64 + j * 16 + lm;
          atomicAdd(&p0[q * 128 + e], acc0[i][j][r]);
          atomicAdd(&p1[q * 128 + e], acc1[i][j][r]);
        }
      }
  }
}

// ---------- epilogue: split-K reduce + all closed-form cost terms ----------
template<bool DIRECT>
__global__ __launch_bounds__(128) void epilogue(
    const float* __restrict__ part,
    const float* __restrict__ negsum, const float* __restrict__ ppsum,
    const float* __restrict__ segsum, const float* __restrict__ nnzb,
    const float* __restrict__ logits, const float* __restrict__ ppos,
    const float* __restrict__ chol, const float* __restrict__ tpos,
    const float* __restrict__ imgsz, float* __restrict__ out)
{
  const int bq = blockIdx.x;          // b*256 + q
  const int b = bq >> 8;
  const int e = threadIdx.x;
  const int qe = (bq & 255) * 128 + e;

  float g1, g2;
  if constexpr (DIRECT) {
    g1 = 0.f; g2 = 0.f;
#pragma unroll 8
    for (int ksi = 0; ksi < 64; ++ksi) {
      g1 += part[((size_t)(ksi * 8 + b) * 2) * 32768 + qe];
      g2 += part[((size_t)(ksi * 8 + b) * 2 + 1) * 32768 + qe];
    }
  } else {
    g1 = part[(size_t)b * 32768 + qe];
    g2 = part[(size_t)(8 + b) * 32768 + qe];
  }

  const float nnz = fmaxf(nnzb[b], 1.f);
  const float mask_cost = (negsum[bq] + g1) / nnz;
  const float dice = 1.f - (2.f * g2 + 1.f) / (ppsum[bq] + segsum[b * 128 + e] + 1.f);
  const float cls = softplus_f(-logits[bq]);
  const float px = ppos[bq * 2], py = ppos[bq * 2 + 1];
  const float tx = tpos[(b * 128 + e) * 2], ty = tpos[(b * 128 + e) * 2 + 1];
  const float dx = px - tx, dy = py - ty;
  const float ax = fabsf(dx), ay = fabsf(dy);
  const float hx = (ax < 1.f) ? 0.5f * dx * dx : ax - 0.5f;
  const float hy = (ay < 1.f) ? 0.5f * dy * dy : ay - 0.5f;
  const float huber = 0.5f * (hx + hy);
  const float sx = imgsz[b * 2], sy = imgsz[b * 2 + 1];
  const float L00 = chol[bq * 4 + 0], L10 = chol[bq * 4 + 2], L11 = chol[bq * 4 + 3];
  const float d0 = (tx - px) * sx, d1 = (ty - py) * sy;
  const float z0 = d0 / L00;
  const float z1 = (d1 - L10 * z0) / L11;
  const float nll = 0.5f * (z0 * z0 + z1 * z1) + 1.8378770664093453f + __logf(L00) + __logf(L11);
  const float lik = 1.f - __expf(-nll);
  out[bq * 128 + e] = 2.f * cls + 5.f * mask_cost + 5.f * dice + huber + 0.5f * nll + 0.5f * lik;
}

// ---------- launcher ----------
extern "C" void kernel_launch(void* const* d_in, const int* in_sizes, int n_in,
                              void* d_out, int out_size, void* d_ws, size_t ws_size,
                              hipStream_t stream)
{
  (void)in_sizes; (void)n_in; (void)out_size;
  const float* logits = (const float*)d_in[0];
  const float* mlv    = (const float*)d_in[1];
  const int*   mask   = (const int*)d_in[2];
  const float* seg    = (const float*)d_in[3];
  const float* ppos   = (const float*)d_in[4];
  const float* chol   = (const float*)d_in[5];
  const float* tpos   = (const float*)d_in[6];
  const float* imgsz  = (const float*)d_in[7];

  char* ws = (char*)d_ws;
  const size_t PART_DIRECT = 134217728ull;              // 64ks*8b*2g*32768*4B
  const size_t NEED = PART_DIRECT + 20512ull;

  if (ws_size >= NEED) {
    float* part   = (float*)ws;
    float* negsum = (float*)(ws + PART_DIRECT);
    float* ppsum  = (float*)(ws + PART_DIRECT + 8192);
    float* segsum = (float*)(ws + PART_DIRECT + 16384);
    float* nnzb   = (float*)(ws + PART_DIRECT + 20480);
    hipMemsetAsync(ws + PART_DIRECT, 0, 20512, stream);  // only the small sums
    fused_all<true><<<512, 512, 0, stream>>>(mlv, mask, seg, part, negsum, ppsum, segsum, nnzb);
    epilogue<true><<<2048, 128, 0, stream>>>(part, negsum, ppsum, segsum, nnzb,
                                             logits, ppos, chol, tpos, imgsz, (float*)d_out);
  } else {
    float* part   = (float*)(ws);                    // [2][8][256][128]
    float* negsum = (float*)(ws + 2097152);
    float* ppsum  = (float*)(ws + 2105344);
    float* segsum = (float*)(ws + 2113536);
    float* nnzb   = (float*)(ws + 2117632);
    hipMemsetAsync(ws, 0, 2117664, stream);
    fused_all<false><<<512, 512, 0, stream>>>(mlv, mask, seg, part, negsum, ppsum, segsum, nnzb);
    epilogue<false><<<2048, 128, 0, stream>>>(part, negsum, ppsum, segsum, nnzb,
                                              logits, ppos, chol, tpos, imgsz, (float*)d_out);
  }
}

// Round 7
// 457.042 us; speedup vs baseline: 1.7900x; 1.7900x over previous
//
#include <hip/hip_runtime.h>
#include <cstdint>
#include <cstddef>

typedef float v4f __attribute__((ext_vector_type(4)));
typedef short short8 __attribute__((ext_vector_type(8)));

constexpr int B_ = 8, P_ = 16384, Q_ = 256, E_ = 128;

// ---------- helpers ----------
__device__ __forceinline__ unsigned int f2bf(float f) {
  unsigned int x = __float_as_uint(f);
  x += 0x7FFFu + ((x >> 16) & 1u);           // round-to-nearest-even
  return x >> 16;
}
__device__ __forceinline__ float softplus_f(float x) {
  return fmaxf(x, 0.f) + __logf(1.f + __expf(-fabsf(x)));
}
__device__ __forceinline__ float wsum(float v) {
#pragma unroll
  for (int o = 32; o; o >>= 1) v += __shfl_xor(v, o, 64);
  return v;
}
// LDS-only barrier (no vmcnt drain) - keeps prefetch loads in flight.
__device__ __forceinline__ void lds_barrier() {
  asm volatile("s_waitcnt lgkmcnt(0)" ::: "memory");
  __builtin_amdgcn_s_barrier();
}

// MFMA fragment load: 8 bf16 (4 words) as 2x ds_read_b64 from a pitch-10 row.
// quads 0-1 read data words (k=0..15); quads 2-3 redirect to the shared zero
// block (k=16..31 of the 16x16x32 MFMA contribute 0 -> effective K=16).
#define ZW 15360
__device__ __forceinline__ short8 ldfrag(const unsigned int* lds, int rowbase, int quad) {
  const int a = (quad < 2) ? (rowbase + 4 * quad) : ZW;
  union { unsigned int u[4]; short8 s; } x;
  *(uint2*)(x.u)     = *(const uint2*)(lds + a);
  *(uint2*)(x.u + 2) = *(const uint2*)(lds + a + 2);
  return x.s;
}

// ---------- fused: prep + both GEMMs, split-K ----------
// R6 lesson: per-SIMD VGPR pool = 512 -> 4 waves/SIMD needs <=128 regs/wave,
// so per-thread acc must be <=64 floats -> 1024-thread blocks (65536 acc
// floats / 1024 = 64). grid = 8b x 32ks = 256 blocks = 1 block/CU, 16 waves
// = 4 waves/SIMD (R6 proved this streams 4 TB/s vs 1.67 at 2 waves/SIMD).
// K-step = 16 p-rows; wave w owns row w entirely (q = l+64j), so per-wave
// state is tiny: prefetch 10 regs, acc 64, ~120 total.
// LDS: double-buffered packed bf16 tiles (pitch-10 rows, k-pair words),
// ONE lds_barrier per iteration; prefetch in flight across it.
template<bool DIRECT>
__global__ __launch_bounds__(1024) void fused_all(
    const float* __restrict__ mlv, const int* __restrict__ mask,
    const float* __restrict__ seg, float* __restrict__ part,
    float* __restrict__ negsum, float* __restrict__ ppsum,
    float* __restrict__ segsum, float* __restrict__ nnzb)
{
  // words: per buffer 7680 = A1[2560] EZ[2560] SB[1280] ST[1280]; x2 buffers;
  // zero block at 15360..15363.
  __shared__ __align__(16) unsigned int lds[15376];   // 61504 B

  const int t = threadIdx.x, w = t >> 6, l = t & 63;
  const int lm = l & 15, quad = l >> 4;
  const int wr = w & 3, wc = w >> 2;          // q-block(64) / e-block(32)
  const int kw = w >> 1, kh = w & 1;          // k-pair word / half for row k=w
  const int b = blockIdx.x >> 5, ks = blockIdx.x & 31;

  if (t < 4) lds[ZW + t] = 0u;                // zero block (visible at 1st barrier)

  v4f acc0[4][2], acc1[4][2];
#pragma unroll
  for (int i = 0; i < 4; ++i)
#pragma unroll
    for (int j = 0; j < 2; ++j) { acc0[i][j] = (v4f)0.f; acc1[i][j] = (v4f)0.f; }
  float accN[4] = {0.f,0.f,0.f,0.f};
  float accP[4] = {0.f,0.f,0.f,0.f};
  float accS[2] = {0.f,0.f};
  float cnt = 0.f;

  // wave w handles global p-row = ks*512 + it*16 + w
  const float* mp = mlv + ((size_t)b * P_ + ks * 512 + w) * Q_ + l;
  const int*   kp = mask + ((size_t)b * P_ + ks * 512 + w) * Q_ + l;
  const float* sp = seg + ((size_t)b * P_ + ks * 512 + w) * E_ + l;

  float X[4]; int M[4]; float S[2];
#pragma unroll
  for (int j = 0; j < 4; ++j) { X[j] = mp[64 * j]; M[j] = kp[64 * j]; }
  S[0] = sp[0]; S[1] = sp[64];

  for (int it = 0; it < 32; ++it) {
    const int bb = (it & 1) * 7680;

    float xs[4]; int ms[4]; float sv[2];
#pragma unroll
    for (int j = 0; j < 4; ++j) { xs[j] = X[j]; ms[j] = M[j]; }
    sv[0] = S[0]; sv[1] = S[1];

    // prefetch next step (in flight across the barrier)
    if (it < 31) {
      mp += 16 * Q_; kp += 16 * Q_; sp += 16 * E_;
#pragma unroll
      for (int j = 0; j < 4; ++j) { X[j] = mp[64 * j]; M[j] = kp[64 * j]; }
      S[0] = sp[0]; S[1] = sp[64];
    }

    // ---- compute row w: softmax pieces + packing ----
    float ez[4], s = 0.f;
#pragma unroll
    for (int j = 0; j < 4; ++j) {
      const float e = ms[j] ? __expf(xs[j]) : 0.f;
      ez[j] = e; s += e;
      accN[j] += __logf(1.f + e);              // softplus(x) on masked
    }
    s = wsum(s);                               // full-row sum (q = 0..255)
    const float inv = (s > 0.f) ? (1.f / s) : 0.f;

    unsigned short* hs = (unsigned short*)lds;
#pragma unroll
    for (int j = 0; j < 4; ++j) {
      const int q = l + 64 * j;
      const float p = ez[j] * inv;
      accP[j] += p;
      hs[(bb + q * 10 + kw) * 2 + kh]        = (unsigned short)f2bf(ms[j] ? -xs[j] : 0.f);
      hs[(bb + 2560 + q * 10 + kw) * 2 + kh] = (unsigned short)f2bf(p);
    }
#pragma unroll
    for (int jj = 0; jj < 2; ++jj) {
      const int e = l + 64 * jj;
      accS[jj] += sv[jj];
      cnt += (sv[jj] > 0.f) ? 1.f : 0.f;
      hs[(bb + 5120 + e * 10 + kw) * 2 + kh] = (sv[jj] > 0.f) ? (unsigned short)0x3F80 : (unsigned short)0;
      hs[(bb + 6400 + e * 10 + kw) * 2 + kh] = (unsigned short)f2bf(sv[jj]);
    }

    lds_barrier();   // pack(it) visible; MFMA(it-1) [other buffer] done

    // ---- MFMA phase: effective K=16 via zero-padded upper half ----
#pragma unroll
    for (int j2 = 0; j2 < 2; ++j2) {
      const int eb = wc * 32 + j2 * 16 + lm;
      const short8 bf0 = ldfrag(lds, bb + 5120 + eb * 10, quad);
      const short8 bf1 = ldfrag(lds, bb + 6400 + eb * 10, quad);
#pragma unroll
      for (int i = 0; i < 4; ++i) {
        const int qa = wr * 64 + i * 16 + lm;
        const short8 af0 = ldfrag(lds, bb + qa * 10, quad);
        const short8 af1 = ldfrag(lds, bb + 2560 + qa * 10, quad);
        acc0[i][j2] = __builtin_amdgcn_mfma_f32_16x16x32_bf16(af0, bf0, acc0[i][j2], 0, 0, 0);
        acc1[i][j2] = __builtin_amdgcn_mfma_f32_16x16x32_bf16(af1, bf1, acc1[i][j2], 0, 0, 0);
      }
    }
  }

  // ---- small reductions (negsum/ppsum/segsum/nnz) ----
  __syncthreads();
  float* fr = (float*)lds;
#pragma unroll
  for (int j = 0; j < 4; ++j) {
    fr[w * 256 + l + 64 * j] = accN[j];
    fr[4096 + w * 256 + l + 64 * j] = accP[j];
  }
#pragma unroll
  for (int jj = 0; jj < 2; ++jj)
    fr[8192 + w * 128 + l + 64 * jj] = accS[jj];
  __syncthreads();
  if (t < 256) {
    float sn = 0.f, sq = 0.f;
#pragma unroll
    for (int k = 0; k < 16; ++k) { sn += fr[k * 256 + t]; sq += fr[4096 + k * 256 + t]; }
    atomicAdd(&negsum[b * 256 + t], sn);
    atomicAdd(&ppsum[b * 256 + t], sq);
  } else if (t < 384) {
    const int e = t - 256;
    float ss = 0.f;
#pragma unroll
    for (int k = 0; k < 16; ++k) ss += fr[8192 + k * 128 + e];
    atomicAdd(&segsum[b * 128 + e], ss);
  }
  cnt = wsum(cnt);
  if (l == 0) atomicAdd(&nnzb[b], cnt);

  // ---- split-K partials ----
  if constexpr (DIRECT) {
    float* p0 = part + ((size_t)(ks * 8 + b) * 2) * 32768;
    float* p1 = p0 + 32768;
#pragma unroll
    for (int i = 0; i < 4; ++i)
#pragma unroll
      for (int r = 0; r < 4; ++r) {
        const int q = wr * 64 + i * 16 + quad * 4 + r;
#pragma unroll
        for (int j2 = 0; j2 < 2; ++j2) {
          const int e = wc * 32 + j2 * 16 + lm;
          p0[q * 128 + e] = acc0[i][j2][r];
          p1[q * 128 + e] = acc1[i][j2][r];
        }
      }
  } else {
    float* p0 = part + (size_t)b * 32768;
    float* p1 = part + (size_t)(8 + b) * 32768;
#pragma unroll
    for (int i = 0; i < 4; ++i)
#pragma unroll
      for (int r = 0; r < 4; ++r) {
        const int q = wr * 64 + i * 16 + quad * 4 + r;
#pragma unroll
        for (int j2 = 0; j2 < 2; ++j2) {
          const int e = wc * 32 + j2 * 16 + lm;
          atomicAdd(&p0[q * 128 + e], acc0[i][j2][r]);
          atomicAdd(&p1[q * 128 + e], acc1[i][j2][r]);
        }
      }
  }
}

// ---------- epilogue: split-K reduce + all closed-form cost terms ----------
template<bool DIRECT>
__global__ __launch_bounds__(128) void epilogue(
    const float* __restrict__ part,
    const float* __restrict__ negsum, const float* __restrict__ ppsum,
    const float* __restrict__ segsum, const float* __restrict__ nnzb,
    const float* __restrict__ logits, const float* __restrict__ ppos,
    const float* __restrict__ chol, const float* __restrict__ tpos,
    const float* __restrict__ imgsz, float* __restrict__ out)
{
  const int bq = blockIdx.x;          // b*256 + q
  const int b = bq >> 8;
  const int e = threadIdx.x;
  const int qe = (bq & 255) * 128 + e;

  float g1, g2;
  if constexpr (DIRECT) {
    g1 = 0.f; g2 = 0.f;
#pragma unroll 8
    for (int ksi = 0; ksi < 32; ++ksi) {
      g1 += part[((size_t)(ksi * 8 + b) * 2) * 32768 + qe];
      g2 += part[((size_t)(ksi * 8 + b) * 2 + 1) * 32768 + qe];
    }
  } else {
    g1 = part[(size_t)b * 32768 + qe];
    g2 = part[(size_t)(8 + b) * 32768 + qe];
  }

  const float nnz = fmaxf(nnzb[b], 1.f);
  const float mask_cost = (negsum[bq] + g1) / nnz;
  const float dice = 1.f - (2.f * g2 + 1.f) / (ppsum[bq] + segsum[b * 128 + e] + 1.f);
  const float cls = softplus_f(-logits[bq]);
  const float px = ppos[bq * 2], py = ppos[bq * 2 + 1];
  const float tx = tpos[(b * 128 + e) * 2], ty = tpos[(b * 128 + e) * 2 + 1];
  const float dx = px - tx, dy = py - ty;
  const float ax = fabsf(dx), ay = fabsf(dy);
  const float hx = (ax < 1.f) ? 0.5f * dx * dx : ax - 0.5f;
  const float hy = (ay < 1.f) ? 0.5f * dy * dy : ay - 0.5f;
  const float huber = 0.5f * (hx + hy);
  const float sx = imgsz[b * 2], sy = imgsz[b * 2 + 1];
  const float L00 = chol[bq * 4 + 0], L10 = chol[bq * 4 + 2], L11 = chol[bq * 4 + 3];
  const float d0 = (tx - px) * sx, d1 = (ty - py) * sy;
  const float z0 = d0 / L00;
  const float z1 = (d1 - L10 * z0) / L11;
  const float nll = 0.5f * (z0 * z0 + z1 * z1) + 1.8378770664093453f + __logf(L00) + __logf(L11);
  const float lik = 1.f - __expf(-nll);
  out[bq * 128 + e] = 2.f * cls + 5.f * mask_cost + 5.f * dice + huber + 0.5f * nll + 0.5f * lik;
}

// ---------- launcher ----------
extern "C" void kernel_launch(void* const* d_in, const int* in_sizes, int n_in,
                              void* d_out, int out_size, void* d_ws, size_t ws_size,
                              hipStream_t stream)
{
  (void)in_sizes; (void)n_in; (void)out_size;
  const float* logits = (const float*)d_in[0];
  const float* mlv    = (const float*)d_in[1];
  const int*   mask   = (const int*)d_in[2];
  const float* seg    = (const float*)d_in[3];
  const float* ppos   = (const float*)d_in[4];
  const float* chol   = (const float*)d_in[5];
  const float* tpos   = (const float*)d_in[6];
  const float* imgsz  = (const float*)d_in[7];

  char* ws = (char*)d_ws;
  const size_t PART_DIRECT = 67108864ull;               // 32ks*8b*2g*32768*4B
  const size_t NEED = PART_DIRECT + 20512ull;

  if (ws_size >= NEED) {
    float* part   = (float*)ws;
    float* negsum = (float*)(ws + PART_DIRECT);
    float* ppsum  = (float*)(ws + PART_DIRECT + 8192);
    float* segsum = (float*)(ws + PART_DIRECT + 16384);
    float* nnzb   = (float*)(ws + PART_DIRECT + 20480);
    hipMemsetAsync(ws + PART_DIRECT, 0, 20512, stream);  // only the small sums
    fused_all<true><<<256, 1024, 0, stream>>>(mlv, mask, seg, part, negsum, ppsum, segsum, nnzb);
    epilogue<true><<<2048, 128, 0, stream>>>(part, negsum, ppsum, segsum, nnzb,
                                             logits, ppos, chol, tpos, imgsz, (float*)d_out);
  } else {
    float* part   = (float*)(ws);                    // [2][8][256][128]
    float* negsum = (float*)(ws + 2097152);
    float* ppsum  = (float*)(ws + 2105344);
    float* segsum = (float*)(ws + 2113536);
    float* nnzb   = (float*)(ws + 2117632);
    hipMemsetAsync(ws, 0, 2117664, stream);
    fused_all<false><<<256, 1024, 0, stream>>>(mlv, mask, seg, part, negsum, ppsum, segsum, nnzb);
    epilogue<false><<<2048, 128, 0, stream>>>(part, negsum, ppsum, segsum, nnzb,
                                              logits, ppos, chol, tpos, imgsz, (float*)d_out);
  }
}